// Round 12
// baseline (491.189 us; speedup 1.0000x reference)
//
#include <hip/hip_runtime.h>
#include <hip/hip_bf16.h>
#include <math.h>

#define Bc 4
#define Sc 2048
#define Dc 1024
#define Hc 16
#define DKc 64
#define DFFc 4096
#define Mc (Bc*Sc)
#define LN_EPS 1e-6f

typedef unsigned short ushort_t;
typedef short bf16x8 __attribute__((ext_vector_type(8)));
typedef float f32x4 __attribute__((ext_vector_type(4)));
typedef float f32x16 __attribute__((ext_vector_type(16)));

typedef __attribute__((address_space(3))) void lds_void_t;
typedef __attribute__((address_space(1))) const void gconst_void_t;

__device__ __forceinline__ void gload_lds16(const void* g, void* l) {
  __builtin_amdgcn_global_load_lds((gconst_void_t*)g, (lds_void_t*)l, 16, 0, 0);
}

__device__ __forceinline__ ushort_t f2bf(float f) {
  union { float f; unsigned int u; } a; a.f = f;
  unsigned int r = a.u + 0x7fffu + ((a.u >> 16) & 1u);
  return (ushort_t)(r >> 16);
}

__device__ __forceinline__ void swapl(unsigned& a, unsigned& b) {
  asm("v_permlane32_swap_b32 %0, %1" : "+v"(a), "+v"(b));
}
__device__ __forceinline__ unsigned cvtpk_bf16(float lo, float hi) {
  unsigned r;
  asm("v_cvt_pk_bf16_f32 %0, %1, %2" : "=v"(r) : "v"(lo), "v"(hi));
  return r;
}

// ---------------- weight transpose + f32->bf16 convert ----------------
__global__ __launch_bounds__(256) void k_transpose_cvt(
    const float* __restrict__ W, ushort_t* __restrict__ WT, int K, int N) {
  __shared__ float t[32][33];
  const int tx = threadIdx.x & 31, ty = threadIdx.x >> 5;
  const int n0 = blockIdx.x * 32, k0 = blockIdx.y * 32;
#pragma unroll
  for (int i = 0; i < 4; ++i)
    t[ty + i * 8][tx] = W[(size_t)(k0 + ty + i * 8) * N + n0 + tx];
  __syncthreads();
#pragma unroll
  for (int i = 0; i < 4; ++i)
    WT[(size_t)(n0 + ty + i * 8) * K + k0 + tx] = f2bf(t[tx][ty + i * 8]);
}

// ---------------- layernorm ----------------
__global__ __launch_bounds__(256) void k_layernorm(
    const float* __restrict__ x, const float* __restrict__ alpha,
    const float* __restrict__ beta, ushort_t* __restrict__ out) {
  const int row = blockIdx.x;
  const int tid = threadIdx.x;
  const int w = tid >> 6, lane = tid & 63;
  const float4 v = ((const float4*)(x + (size_t)row * Dc))[tid];
  float s = v.x + v.y + v.z + v.w;
#pragma unroll
  for (int m = 32; m >= 1; m >>= 1) s += __shfl_xor(s, m, 64);
  __shared__ float ws[8];
  if (lane == 0) ws[w] = s;
  __syncthreads();
  s = ws[0] + ws[1] + ws[2] + ws[3];
  const float mean = s * (1.0f / Dc);
  const float dx = v.x - mean, dy = v.y - mean, dz = v.z - mean, dw = v.w - mean;
  float ss = dx * dx + dy * dy + dz * dz + dw * dw;
#pragma unroll
  for (int m = 32; m >= 1; m >>= 1) ss += __shfl_xor(ss, m, 64);
  if (lane == 0) ws[4 + w] = ss;
  __syncthreads();
  ss = ws[4] + ws[5] + ws[6] + ws[7];
  const float stdv = sqrtf(ss / (float)(Dc - 1));
  const float inv = 1.0f / (stdv + LN_EPS);
  const float4 a = ((const float4*)alpha)[tid];
  const float4 b = ((const float4*)beta)[tid];
  ushort4 o;
  o.x = f2bf(a.x * dx * inv + b.x);
  o.y = f2bf(a.y * dy * inv + b.y);
  o.z = f2bf(a.z * dz * inv + b.z);
  o.w = f2bf(a.w * dw * inv + b.w);
  *(ushort4*)(out + (size_t)row * Dc + tid * 4) = o;
}

// ---- bf16 GEMM v3: 256x128 tile, 4 waves, per-wave 128x64 output ----
// Rationale: per K-step a wave now does 32 MFMA on 12 ds_read_b128 (was 16 on 8)
// -> LDS-read:MFMA cycle ratio drops ~2.1x (the v2 bottleneck). Same verified
// 3-buffer counted-vmcnt pipeline (6 loads/tile; vmcnt(6) steady), both-sides
// swizzle, ONE barrier/iter (3 bufs: ds_reads are lgkm-consumed by MFMA before
// each wave reaches the next barrier, so restage is race-free).
// MODE 1: f32 out + resid. 2: tanh-gelu -> bf16. 4: fused QKV.
template <int MODE>
__global__ __launch_bounds__(256, 2) void k_gemm9(
    const ushort_t* __restrict__ A, const ushort_t* __restrict__ BT,
    const float* __restrict__ bias, const float* __restrict__ bias2,
    const float* __restrict__ bias3, const float* __restrict__ resid,
    void* __restrict__ Cout, void* __restrict__ Cout2, void* __restrict__ Cout3,
    int N, int K, int nxn) {
  __shared__ __align__(16) ushort_t As[3][256 * 32];  // 16KB x3
  __shared__ __align__(16) ushort_t Bs[3][128 * 32];  // 8KB x3 (72KB total)
  const int tid = threadIdx.x;
  const int lane = tid & 63;
  const int wid = tid >> 6;                  // 4 waves
  const int wm = wid >> 1, wn = wid & 1;     // 2M x 2N; per-wave 128x64
  const int lrow = lane & 15, lgrp = lane >> 4;
  const int xcd = blockIdx.x & 7;
  const int idx = blockIdx.x >> 3;
  const int in_ = xcd * nxn + idx % nxn;
  const int im = idx / nxn;
  const int m0 = im << 8, n0 = in_ << 7;

  const f32x4 zero4 = {0.f, 0.f, 0.f, 0.f};
  f32x4 acc[8][4];
#pragma unroll
  for (int i = 0; i < 8; ++i)
#pragma unroll
    for (int j = 0; j < 4; ++j) acc[i][j] = zero4;

  // staging: A = 4 sweeps of 256 chunks (rows ar+s*64), B = 2 sweeps.
  // swizzle invariant across sweeps: ((ar+s*64)>>1)&3 == (ar>>1)&3.
  const int ar = tid >> 2;
  const int as0 = (tid & 3) ^ ((ar >> 1) & 3);
  const ushort_t* Ag = A + (size_t)(m0 + ar) * K + as0 * 8;
  const ushort_t* Bg = BT + (size_t)(n0 + ar) * K + as0 * 8;
  char* const a_w = (char*)(&As[0][0]) + wid * 1024;  // + bi*16384 + s*4096
  char* const b_w = (char*)(&Bs[0][0]) + wid * 1024;  // + bi*8192  + s*4096

  // frag read offsets (ushort units), swizzled slot (2-way max = free)
  const int sl = lgrp ^ ((lrow >> 1) & 3);
  const int aoff = (wm * 128 + lrow) * 32 + sl * 8;   // + mf*512
  const int boff = (wn * 64 + lrow) * 32 + sl * 8;    // + nf*512

  const int nk = K >> 5;
  const size_t K64 = (size_t)64 * K;

  // prologue: tiles 0,1 (12 loads in flight)
#pragma unroll
  for (int tt = 0; tt < 2; ++tt) {
    const size_t ko = (size_t)tt * 32;
#pragma unroll
    for (int s = 0; s < 4; ++s)
      gload_lds16(Ag + ko + s * K64, a_w + tt * 16384 + s * 4096);
#pragma unroll
    for (int s = 0; s < 2; ++s)
      gload_lds16(Bg + ko + s * K64, b_w + tt * 8192 + s * 4096);
  }
  int cur = 0;
  for (int t = 0; t < nk; ++t) {
    if (t + 1 < nk) { asm volatile("s_waitcnt vmcnt(6)" ::: "memory"); }
    else            { asm volatile("s_waitcnt vmcnt(0)" ::: "memory"); }
    asm volatile("s_barrier" ::: "memory");   // tile t resident for all waves
    const ushort_t* Ab = &As[cur][0];
    const ushort_t* Bb = &Bs[cur][0];
    bf16x8 af[8], bf[4];
#pragma unroll
    for (int mf = 0; mf < 8; ++mf) af[mf] = *(const bf16x8*)(Ab + aoff + mf * 512);
#pragma unroll
    for (int nf = 0; nf < 4; ++nf) bf[nf] = *(const bf16x8*)(Bb + boff + nf * 512);
    if (t + 2 < nk) {                         // stage tile t+2 (read finished at t-1)
      const int bi = (cur + 2 >= 3) ? cur - 1 : cur + 2;
      const size_t ko = (size_t)(t + 2) * 32;
#pragma unroll
      for (int s = 0; s < 4; ++s)
        gload_lds16(Ag + ko + s * K64, a_w + bi * 16384 + s * 4096);
#pragma unroll
      for (int s = 0; s < 2; ++s)
        gload_lds16(Bg + ko + s * K64, b_w + bi * 8192 + s * 4096);
    }
    __builtin_amdgcn_s_setprio(1);
#pragma unroll
    for (int mf = 0; mf < 8; ++mf)
#pragma unroll
      for (int nf = 0; nf < 4; ++nf)
        acc[mf][nf] = __builtin_amdgcn_mfma_f32_16x16x32_bf16(af[mf], bf[nf], acc[mf][nf], 0, 0, 0);
    __builtin_amdgcn_s_setprio(0);
    cur = (cur + 1 == 3) ? 0 : cur + 1;
  }

  // ---------------- epilogue ----------------
  const float* bsrc = bias;
  int n0l = n0;
  int seg = 0;
  if (MODE == 4) {
    seg = n0 >> 10;
    n0l = n0 & 1023;
    bsrc = (seg == 0) ? bias : (seg == 1 ? bias2 : bias3);
  }
  float bv[4];
#pragma unroll
  for (int n = 0; n < 4; ++n) bv[n] = bsrc[n0l + wn * 64 + n * 16 + lrow];

#pragma unroll
  for (int m = 0; m < 8; ++m)
#pragma unroll
    for (int n = 0; n < 4; ++n) {
      if (MODE == 4 && seg == 2) {
        const size_t s0 = (size_t)(m0 + wm * 128 + m * 16 + lgrp * 4);
        const int gb = (int)(s0 >> 11);
        const int ss = (int)(s0 & 2047);
        const int col = n0l + wn * 64 + n * 16 + lrow;
        const int hh = col >> 6, dd = col & 63;
        ushort4 o4;
        o4.x = f2bf(acc[m][n][0] + bv[n]);
        o4.y = f2bf(acc[m][n][1] + bv[n]);
        o4.z = f2bf(acc[m][n][2] + bv[n]);
        o4.w = f2bf(acc[m][n][3] + bv[n]);
        *(ushort4*)((ushort_t*)Cout3 + ((size_t)(gb * Hc + hh) * DKc + dd) * Sc + ss) = o4;
      } else if (MODE == 4) {
        ushort_t* Co = (seg == 0) ? (ushort_t*)Cout : (ushort_t*)Cout2;
        const int col = n0l + wn * 64 + n * 16 + lrow;
#pragma unroll
        for (int r = 0; r < 4; ++r) {
          const size_t row = (size_t)(m0 + wm * 128 + m * 16 + lgrp * 4 + r);
          Co[row * Dc + col] = f2bf(acc[m][n][r] + bv[n]);
        }
      } else {
#pragma unroll
        for (int r = 0; r < 4; ++r) {
          const size_t row = (size_t)(m0 + wm * 128 + m * 16 + lgrp * 4 + r);
          const size_t col = (size_t)(n0 + wn * 64 + n * 16 + lrow);
          float v = acc[m][n][r] + bv[n];
          if (MODE == 2) {
            const float u = 0.7978845608f * (v + 0.044715f * v * v * v);
            const float e = exp2f(2.885390082f * u);
            const float th = 1.0f - 2.0f * __frcp_rn(e + 1.0f);
            v = 0.5f * v * (1.0f + th);
          }
          if (MODE == 1) {
            v += resid[row * N + col];
            ((float*)Cout)[row * N + col] = v;
          } else {
            ((ushort_t*)Cout)[row * N + col] = f2bf(v);
          }
        }
      }
    }
}

// ---------------- additive mask, log2 domain, fixed-max M=8 folded in ----------------
__global__ __launch_bounds__(256) void k_maskadd(const int* __restrict__ mask,
                                                float* __restrict__ madd, int n) {
  const int i = blockIdx.x * 256 + threadIdx.x;
  if (i < n) madd[i] = mask[i] ? -8.0f : -1.442695041e9f;
}

// ---- flash attention v9 (unchanged from R11) ----
#define KSCALE 0.1803368801e0f  /* 0.125 * log2(e) */
__global__ __launch_bounds__(256) void k_attn9(
    const ushort_t* __restrict__ Qb, const ushort_t* __restrict__ Kb,
    const ushort_t* __restrict__ Vt, const float* __restrict__ madd,
    ushort_t* __restrict__ Ob) {
  __shared__ __align__(16) ushort_t Ks[3][32 * 64];
  __shared__ __align__(16) ushort_t Vs[3][64 * 32];
  __shared__ __align__(16) float Ms[Sc];

  const int bid = blockIdx.x;
  const int xcd = bid & 7, idx = bid >> 3;
  const int bh = xcd * 8 + (idx >> 4);
  const int qb = idx & 15;
  const int b = bh >> 4, h = bh & 15;
  const int tid = threadIdx.x;
  const int lane = tid & 63, w = tid >> 6;
  const int l31 = lane & 31, hi = lane >> 5;
  const size_t bS = (size_t)b * Sc;
  const int qrow0 = qb * 128 + w * 32;

  bf16x8 qf[4];
  const ushort_t* qp = Qb + (bS + qrow0 + l31) * Dc + h * DKc + hi * 8;
#pragma unroll
  for (int c = 0; c < 4; ++c) qf[c] = *(const bf16x8*)(qp + c * 16);

  bf16x8 ones;
#pragma unroll
  for (int i = 0; i < 8; ++i) ones[i] = (short)0x3F80;

  f32x16 accA, accB, accS;
#pragma unroll
  for (int i = 0; i < 16; ++i) { accA[i] = 0.f; accB[i] = 0.f; accS[i] = 0.f; }

  const ushort_t* Vth = Vt + (size_t)bh * (DKc * Sc);
  const float* mp = madd + b * Sc;

  const int kr = tid >> 3, ksl = (tid & 7) ^ (kr & 7);
  const int vr = tid >> 2, vsl = (tid & 3) ^ ((vr >> 1) & 3);
  const ushort_t* Kg = Kb + (bS + kr) * Dc + h * DKc + ksl * 8;
  const ushort_t* Vg = Vth + (size_t)vr * Sc + vsl * 8;
  char* const k_w = (char*)(&Ks[0][0]) + w * 1024;
  char* const v_w = (char*)(&Vs[0][0]) + w * 1024;

  gload_lds16(mp + tid * 4, (char*)Ms + w * 1024);
  gload_lds16(mp + (tid + 256) * 4, (char*)Ms + 4096 + w * 1024);
  gload_lds16(Kg, k_w);
  gload_lds16(Vg, v_w);
  gload_lds16(Kg + (size_t)32 * Dc, k_w + 4096);
  gload_lds16(Vg + 32, v_w + 4096);

  const int vsw = (l31 >> 1) & 3;
  int cur = 0;
  for (int t = 0; t < 64; ++t) {
    if (t < 63) { asm volatile("s_waitcnt vmcnt(2)" ::: "memory"); }
    else        { asm volatile("s_waitcnt vmcnt(0)" ::: "memory"); }
    asm volatile("s_barrier" ::: "memory");
    const char* Kbuf = (const char*)(&Ks[cur][0]);
    const char* Vbuf = (const char*)(&Vs[cur][0]);
    bf16x8 kf[4];
#pragma unroll
    for (int c = 0; c < 4; ++c) {
      const int slr = (c * 2 + hi) ^ (l31 & 7);
      kf[c] = *(const bf16x8*)(Kbuf + l31 * 128 + slr * 16);
    }
    const bf16x8 v00 = *(const bf16x8*)(Vbuf + l31 * 64 + ((hi ^ vsw) * 16));
    const bf16x8 v01 = *(const bf16x8*)(Vbuf + l31 * 64 + (((2 + hi) ^ vsw) * 16));
    const bf16x8 v10 = *(const bf16x8*)(Vbuf + (32 + l31) * 64 + ((hi ^ vsw) * 16));
    const bf16x8 v11 = *(const bf16x8*)(Vbuf + (32 + l31) * 64 + (((2 + hi) ^ vsw) * 16));
    float4 mv[4];
#pragma unroll
    for (int c = 0; c < 4; ++c)
      mv[c] = *(const float4*)(&Ms[t * 32 + c * 8 + 4 * hi]);
    if (t + 2 < 64) {
      const int bi = (cur + 2 >= 3) ? cur - 1 : cur + 2;
      const size_t kv2 = (size_t)(t + 2) * 32;
      gload_lds16(Kg + kv2 * Dc, k_w + bi * 4096);
      gload_lds16(Vg + kv2, v_w + bi * 4096);
    }
    f32x16 sc;
#pragma unroll
    for (int i = 0; i < 16; ++i) sc[i] = 0.f;
    __builtin_amdgcn_s_setprio(1);
    sc = __builtin_amdgcn_mfma_f32_32x32x16_bf16(kf[0], qf[0], sc, 0, 0, 0);
    sc = __builtin_amdgcn_mfma_f32_32x32x16_bf16(kf[1], qf[1], sc, 0, 0, 0);
    sc = __builtin_amdgcn_mfma_f32_32x32x16_bf16(kf[2], qf[2], sc, 0, 0, 0);
    sc = __builtin_amdgcn_mfma_f32_32x32x16_bf16(kf[3], qf[3], sc, 0, 0, 0);
    __builtin_amdgcn_s_setprio(0);
    float p[16];
    p[0] = exp2f(sc[0] * KSCALE + mv[0].x);  p[1] = exp2f(sc[1] * KSCALE + mv[0].y);
    p[2] = exp2f(sc[2] * KSCALE + mv[0].z);  p[3] = exp2f(sc[3] * KSCALE + mv[0].w);
    p[4] = exp2f(sc[4] * KSCALE + mv[1].x);  p[5] = exp2f(sc[5] * KSCALE + mv[1].y);
    p[6] = exp2f(sc[6] * KSCALE + mv[1].z);  p[7] = exp2f(sc[7] * KSCALE + mv[1].w);
    p[8] = exp2f(sc[8] * KSCALE + mv[2].x);  p[9] = exp2f(sc[9] * KSCALE + mv[2].y);
    p[10] = exp2f(sc[10] * KSCALE + mv[2].z); p[11] = exp2f(sc[11] * KSCALE + mv[2].w);
    p[12] = exp2f(sc[12] * KSCALE + mv[3].x); p[13] = exp2f(sc[13] * KSCALE + mv[3].y);
    p[14] = exp2f(sc[14] * KSCALE + mv[3].z); p[15] = exp2f(sc[15] * KSCALE + mv[3].w);
    unsigned cw[4][2];
#pragma unroll
    for (int a = 0; a < 4; ++a) {
      cw[a][0] = cvtpk_bf16(p[4 * a + 0], p[4 * a + 1]);
      cw[a][1] = cvtpk_bf16(p[4 * a + 2], p[4 * a + 3]);
    }
    unsigned a00 = cw[0][0], b00 = cw[1][0]; swapl(a00, b00);
    unsigned a01 = cw[0][1], b01 = cw[1][1]; swapl(a01, b01);
    unsigned a10 = cw[2][0], b10 = cw[3][0]; swapl(a10, b10);
    unsigned a11 = cw[2][1], b11 = cw[3][1]; swapl(a11, b11);
    union { unsigned u[4]; bf16x8 v; } pa0, pa1;
    pa0.u[0] = a00; pa0.u[1] = a01; pa0.u[2] = b00; pa0.u[3] = b01;
    pa1.u[0] = a10; pa1.u[1] = a11; pa1.u[2] = b10; pa1.u[3] = b11;
    __builtin_amdgcn_s_setprio(1);
    accA = __builtin_amdgcn_mfma_f32_32x32x16_bf16(pa0.v, v00, accA, 0, 0, 0);
    accA = __builtin_amdgcn_mfma_f32_32x32x16_bf16(pa1.v, v01, accA, 0, 0, 0);
    accB = __builtin_amdgcn_mfma_f32_32x32x16_bf16(pa0.v, v10, accB, 0, 0, 0);
    accB = __builtin_amdgcn_mfma_f32_32x32x16_bf16(pa1.v, v11, accB, 0, 0, 0);
    accS = __builtin_amdgcn_mfma_f32_32x32x16_bf16(pa0.v, ones, accS, 0, 0, 0);
    accS = __builtin_amdgcn_mfma_f32_32x32x16_bf16(pa1.v, ones, accS, 0, 0, 0);
    __builtin_amdgcn_s_setprio(0);
    cur = (cur + 1 == 3) ? 0 : cur + 1;
  }

#pragma unroll
  for (int r = 0; r < 16; ++r) {
    const int q = (r & 3) + 8 * (r >> 2) + 4 * hi;
    const float inv = 1.0f / accS[r];
    ushort_t* op = Ob + (bS + qrow0 + q) * Dc + h * DKc + l31;
    op[0] = f2bf(accA[r] * inv);
    op[32] = f2bf(accB[r] * inv);
  }
}

// ---------------- launcher ----------------
extern "C" void kernel_launch(void* const* d_in, const int* in_sizes, int n_in,
                              void* d_out, int out_size, void* d_ws, size_t ws_size,
                              hipStream_t stream) {
  const float* x     = (const float*)d_in[0];
  const int* mask    = (const int*)d_in[1];
  const float* wq_w  = (const float*)d_in[2];
  const float* wq_b  = (const float*)d_in[3];
  const float* wk_w  = (const float*)d_in[4];
  const float* wk_b  = (const float*)d_in[5];
  const float* wv_w  = (const float*)d_in[6];
  const float* wv_b  = (const float*)d_in[7];
  const float* wo_w  = (const float*)d_in[8];
  const float* wo_b  = (const float*)d_in[9];
  const float* ff_w0 = (const float*)d_in[10];
  const float* ff_b0 = (const float*)d_in[11];
  const float* ff_w1 = (const float*)d_in[12];
  const float* ff_b1 = (const float*)d_in[13];
  const float* ln0_a = (const float*)d_in[14];
  const float* ln0_b = (const float*)d_in[15];
  const float* ln1_a = (const float*)d_in[16];
  const float* ln1_b = (const float*)d_in[17];
  float* out = (float*)d_out;

  char* ws = (char*)d_ws;
  size_t off = 0;
  ushort_t* WTq = (ushort_t*)(ws + off); off += (size_t)Dc * Dc * 2;   // [3072,1024] packed
  ushort_t* WTk = (ushort_t*)(ws + off); off += (size_t)Dc * Dc * 2;
  ushort_t* WTv = (ushort_t*)(ws + off); off += (size_t)Dc * Dc * 2;
  ushort_t* WTo = (ushort_t*)(ws + off); off += (size_t)Dc * Dc * 2;
  ushort_t* WT0 = (ushort_t*)(ws + off); off += (size_t)DFFc * Dc * 2;
  ushort_t* WT1 = (ushort_t*)(ws + off); off += (size_t)Dc * DFFc * 2;
  ushort_t* hbuf = (ushort_t*)(ws + off); off += (size_t)Mc * Dc * 2;
  ushort_t* qbuf = (ushort_t*)(ws + off); off += (size_t)Mc * Dc * 2;
  ushort_t* kbuf = (ushort_t*)(ws + off); off += (size_t)Mc * Dc * 2;
  ushort_t* vtb  = (ushort_t*)(ws + off); off += (size_t)Mc * Dc * 2;  // Vt [B,H,DK,S]
  ushort_t* abuf = (ushort_t*)(ws + off); off += (size_t)Mc * Dc * 2;
  float* maddb   = (float*)(ws + off);   off += (size_t)Bc * Sc * 4;
  ushort_t* gbuf = qbuf;  // overlays dead q/k/vt buffers

  const dim3 blk(256);
  k_transpose_cvt<<<dim3(Dc / 32, Dc / 32), blk, 0, stream>>>(wq_w, WTq, Dc, Dc);
  k_transpose_cvt<<<dim3(Dc / 32, Dc / 32), blk, 0, stream>>>(wk_w, WTk, Dc, Dc);
  k_transpose_cvt<<<dim3(Dc / 32, Dc / 32), blk, 0, stream>>>(wv_w, WTv, Dc, Dc);
  k_transpose_cvt<<<dim3(Dc / 32, Dc / 32), blk, 0, stream>>>(wo_w, WTo, Dc, Dc);
  k_transpose_cvt<<<dim3(DFFc / 32, Dc / 32), blk, 0, stream>>>(ff_w0, WT0, Dc, DFFc);
  k_transpose_cvt<<<dim3(Dc / 32, DFFc / 32), blk, 0, stream>>>(ff_w1, WT1, DFFc, Dc);
  k_maskadd<<<dim3((Bc * Sc + 255) / 256), blk, 0, stream>>>(mask, maddb, Bc * Sc);
  // LN0
  k_layernorm<<<Mc, blk, 0, stream>>>(x, ln0_a, ln0_b, hbuf);
  // fused QKV projection: [8192,3072] -> 32 m-blocks x 24 n-blocks
  k_gemm9<4><<<dim3(768), blk, 0, stream>>>(hbuf, WTq, wq_b, wk_b, wv_b, nullptr,
                                            qbuf, kbuf, vtb, 3072, Dc, 3);
  // attention (LDS-staged K/V, fixed-max softmax, ones-MFMA rowsum)
  k_attn9<<<dim3(1024), blk, 0, stream>>>(qbuf, kbuf, vtb, maddb, abuf);
  // O projection + residual(x) -> d_out (f32): 32 x 8
  k_gemm9<1><<<dim3(256), blk, 0, stream>>>(abuf, WTo, wo_b, nullptr, nullptr, x,
                                            out, nullptr, nullptr, Dc, Dc, 1);
  // LN1
  k_layernorm<<<Mc, blk, 0, stream>>>(out, ln1_a, ln1_b, hbuf);
  // FFN0 + tanh-GELU -> gbuf (bf16): 32 x 32
  k_gemm9<2><<<dim3(1024), blk, 0, stream>>>(hbuf, WT0, ff_b0, nullptr, nullptr, nullptr,
                                             gbuf, nullptr, nullptr, DFFc, Dc, 4);
  // FFN1 + residual(d_out) -> d_out (f32): 32 x 8
  k_gemm9<1><<<dim3(256), blk, 0, stream>>>(gbuf, WT1, ff_b1, nullptr, nullptr, out,
                                            out, nullptr, nullptr, Dc, DFFc, 1);
}

// Round 13
// 466.265 us; speedup vs baseline: 1.0535x; 1.0535x over previous
//
#include <hip/hip_runtime.h>
#include <hip/hip_bf16.h>
#include <math.h>

#define Bc 4
#define Sc 2048
#define Dc 1024
#define Hc 16
#define DKc 64
#define DFFc 4096
#define Mc (Bc*Sc)
#define LN_EPS 1e-6f

typedef unsigned short ushort_t;
typedef short bf16x8 __attribute__((ext_vector_type(8)));
typedef float f32x4 __attribute__((ext_vector_type(4)));
typedef float f32x16 __attribute__((ext_vector_type(16)));

typedef __attribute__((address_space(3))) void lds_void_t;
typedef __attribute__((address_space(1))) const void gconst_void_t;

__device__ __forceinline__ void gload_lds16(const void* g, void* l) {
  __builtin_amdgcn_global_load_lds((gconst_void_t*)g, (lds_void_t*)l, 16, 0, 0);
}

__device__ __forceinline__ ushort_t f2bf(float f) {
  union { float f; unsigned int u; } a; a.f = f;
  unsigned int r = a.u + 0x7fffu + ((a.u >> 16) & 1u);
  return (ushort_t)(r >> 16);
}

__device__ __forceinline__ void swapl(unsigned& a, unsigned& b) {
  asm("v_permlane32_swap_b32 %0, %1" : "+v"(a), "+v"(b));
}
__device__ __forceinline__ unsigned cvtpk_bf16(float lo, float hi) {
  unsigned r;
  asm("v_cvt_pk_bf16_f32 %0, %1, %2" : "=v"(r) : "v"(lo), "v"(hi));
  return r;
}

// ---------------- weight transpose + f32->bf16 convert ----------------
__global__ __launch_bounds__(256) void k_transpose_cvt(
    const float* __restrict__ W, ushort_t* __restrict__ WT, int K, int N) {
  __shared__ float t[32][33];
  const int tx = threadIdx.x & 31, ty = threadIdx.x >> 5;
  const int n0 = blockIdx.x * 32, k0 = blockIdx.y * 32;
#pragma unroll
  for (int i = 0; i < 4; ++i)
    t[ty + i * 8][tx] = W[(size_t)(k0 + ty + i * 8) * N + n0 + tx];
  __syncthreads();
#pragma unroll
  for (int i = 0; i < 4; ++i)
    WT[(size_t)(n0 + ty + i * 8) * K + k0 + tx] = f2bf(t[tx][ty + i * 8]);
}

// ---------------- layernorm ----------------
__global__ __launch_bounds__(256) void k_layernorm(
    const float* __restrict__ x, const float* __restrict__ alpha,
    const float* __restrict__ beta, ushort_t* __restrict__ out) {
  const int row = blockIdx.x;
  const int tid = threadIdx.x;
  const int w = tid >> 6, lane = tid & 63;
  const float4 v = ((const float4*)(x + (size_t)row * Dc))[tid];
  float s = v.x + v.y + v.z + v.w;
#pragma unroll
  for (int m = 32; m >= 1; m >>= 1) s += __shfl_xor(s, m, 64);
  __shared__ float ws[8];
  if (lane == 0) ws[w] = s;
  __syncthreads();
  s = ws[0] + ws[1] + ws[2] + ws[3];
  const float mean = s * (1.0f / Dc);
  const float dx = v.x - mean, dy = v.y - mean, dz = v.z - mean, dw = v.w - mean;
  float ss = dx * dx + dy * dy + dz * dz + dw * dw;
#pragma unroll
  for (int m = 32; m >= 1; m >>= 1) ss += __shfl_xor(ss, m, 64);
  if (lane == 0) ws[4 + w] = ss;
  __syncthreads();
  ss = ws[4] + ws[5] + ws[6] + ws[7];
  const float stdv = sqrtf(ss / (float)(Dc - 1));
  const float inv = 1.0f / (stdv + LN_EPS);
  const float4 a = ((const float4*)alpha)[tid];
  const float4 b = ((const float4*)beta)[tid];
  ushort4 o;
  o.x = f2bf(a.x * dx * inv + b.x);
  o.y = f2bf(a.y * dy * inv + b.y);
  o.z = f2bf(a.z * dz * inv + b.z);
  o.w = f2bf(a.w * dw * inv + b.w);
  *(ushort4*)(out + (size_t)row * Dc + tid * 4) = o;
}

// ---- bf16 GEMM v2 (REVERTED to R11-verified): 256x128, 8 waves, 3-buffer vmcnt(3) ----
template <int MODE>
__global__ __launch_bounds__(512, 4) void k_gemm8(
    const ushort_t* __restrict__ A, const ushort_t* __restrict__ BT,
    const float* __restrict__ bias, const float* __restrict__ bias2,
    const float* __restrict__ bias3, const float* __restrict__ resid,
    void* __restrict__ Cout, void* __restrict__ Cout2, void* __restrict__ Cout3,
    int N, int K, int nxn) {
  __shared__ __align__(16) ushort_t As[3][256 * 32];
  __shared__ __align__(16) ushort_t Bs[3][128 * 32];
  const int tid = threadIdx.x;
  const int lane = tid & 63;
  const int wid = tid >> 6;
  const int wm = wid >> 1, wn = wid & 1;
  const int lrow = lane & 15, lgrp = lane >> 4;
  const int xcd = blockIdx.x & 7;
  const int idx = blockIdx.x >> 3;
  const int in_ = xcd * nxn + idx % nxn;
  const int im = idx / nxn;
  const int m0 = im << 8, n0 = in_ << 7;

  const f32x4 zero4 = {0.f, 0.f, 0.f, 0.f};
  f32x4 acc[4][4];
#pragma unroll
  for (int i = 0; i < 4; ++i)
#pragma unroll
    for (int j = 0; j < 4; ++j) acc[i][j] = zero4;

  const int ar0 = tid >> 2;
  const int as0 = (tid & 3) ^ ((ar0 >> 1) & 3);
  const int ar1 = ar0 + 128;
  const ushort_t* Ag0 = A + (size_t)(m0 + ar0) * K + as0 * 8;
  const ushort_t* Ag1 = A + (size_t)(m0 + ar1) * K + as0 * 8;
  const ushort_t* Bg0 = BT + (size_t)(n0 + ar0 % 128) * K + as0 * 8;
  char* const a_w = (char*)(&As[0][0]) + wid * 1024;
  char* const b_w = (char*)(&Bs[0][0]) + wid * 1024;

  const int sl = lgrp ^ ((lrow >> 1) & 3);
  const int aoff = (wm * 64 + lrow) * 32 + sl * 8;
  const int boff = (wn * 64 + lrow) * 32 + sl * 8;

  const int nk = K >> 5;
  {
    gload_lds16(Ag0, a_w);
    gload_lds16(Ag1, a_w + 8192);
    gload_lds16(Bg0, b_w);
    gload_lds16(Ag0 + 32, a_w + 16384);
    gload_lds16(Ag1 + 32, a_w + 16384 + 8192);
    gload_lds16(Bg0 + 32, b_w + 8192);
  }
  int cur = 0;
  for (int t = 0; t < nk; ++t) {
    if (t + 1 < nk) { asm volatile("s_waitcnt vmcnt(3)" ::: "memory"); }
    else            { asm volatile("s_waitcnt vmcnt(0)" ::: "memory"); }
    asm volatile("s_barrier" ::: "memory");
    const ushort_t* Ab = &As[cur][0];
    const ushort_t* Bb = &Bs[cur][0];
    bf16x8 af[4], bf[4];
#pragma unroll
    for (int mf = 0; mf < 4; ++mf) af[mf] = *(const bf16x8*)(Ab + aoff + mf * 512);
#pragma unroll
    for (int nf = 0; nf < 4; ++nf) bf[nf] = *(const bf16x8*)(Bb + boff + nf * 512);
    if (t + 2 < nk) {
      const int bi = (cur + 2 >= 3) ? cur - 1 : cur + 2;
      const size_t ko = (size_t)(t + 2) * 32;
      gload_lds16(Ag0 + ko, a_w + bi * 16384);
      gload_lds16(Ag1 + ko, a_w + bi * 16384 + 8192);
      gload_lds16(Bg0 + ko, b_w + bi * 8192);
    }
    __builtin_amdgcn_s_setprio(1);
#pragma unroll
    for (int mf = 0; mf < 4; ++mf)
#pragma unroll
      for (int nf = 0; nf < 4; ++nf)
        acc[mf][nf] = __builtin_amdgcn_mfma_f32_16x16x32_bf16(af[mf], bf[nf], acc[mf][nf], 0, 0, 0);
    __builtin_amdgcn_s_setprio(0);
    asm volatile("s_barrier" ::: "memory");
    cur = (cur + 1 == 3) ? 0 : cur + 1;
  }

  const float* bsrc = bias;
  int n0l = n0;
  int seg = 0;
  if (MODE == 4) {
    seg = n0 >> 10;
    n0l = n0 & 1023;
    bsrc = (seg == 0) ? bias : (seg == 1 ? bias2 : bias3);
  }
  float bv[4];
#pragma unroll
  for (int n = 0; n < 4; ++n) bv[n] = bsrc[n0l + wn * 64 + n * 16 + lrow];

#pragma unroll
  for (int m = 0; m < 4; ++m)
#pragma unroll
    for (int n = 0; n < 4; ++n) {
      if (MODE == 4 && seg == 2) {
        const size_t s0 = (size_t)(m0 + wm * 64 + m * 16 + lgrp * 4);
        const int gb = (int)(s0 >> 11);
        const int ss = (int)(s0 & 2047);
        const int col = n0l + wn * 64 + n * 16 + lrow;
        const int hh = col >> 6, dd = col & 63;
        ushort4 o4;
        o4.x = f2bf(acc[m][n][0] + bv[n]);
        o4.y = f2bf(acc[m][n][1] + bv[n]);
        o4.z = f2bf(acc[m][n][2] + bv[n]);
        o4.w = f2bf(acc[m][n][3] + bv[n]);
        *(ushort4*)((ushort_t*)Cout3 + ((size_t)(gb * Hc + hh) * DKc + dd) * Sc + ss) = o4;
      } else if (MODE == 4) {
        ushort_t* Co = (seg == 0) ? (ushort_t*)Cout : (ushort_t*)Cout2;
        const int col = n0l + wn * 64 + n * 16 + lrow;
#pragma unroll
        for (int r = 0; r < 4; ++r) {
          const size_t row = (size_t)(m0 + wm * 64 + m * 16 + lgrp * 4 + r);
          Co[row * Dc + col] = f2bf(acc[m][n][r] + bv[n]);
        }
      } else {
#pragma unroll
        for (int r = 0; r < 4; ++r) {
          const size_t row = (size_t)(m0 + wm * 64 + m * 16 + lgrp * 4 + r);
          const size_t col = (size_t)(n0 + wn * 64 + n * 16 + lrow);
          float v = acc[m][n][r] + bv[n];
          if (MODE == 2) {
            const float u = 0.7978845608f * (v + 0.044715f * v * v * v);
            const float e = exp2f(2.885390082f * u);
            const float th = 1.0f - 2.0f * __frcp_rn(e + 1.0f);
            v = 0.5f * v * (1.0f + th);
          }
          if (MODE == 1) {
            v += resid[row * N + col];
            ((float*)Cout)[row * N + col] = v;
          } else {
            ((ushort_t*)Cout)[row * N + col] = f2bf(v);
          }
        }
      }
    }
}

// ---------------- additive mask, log2 domain, fixed-max M=8 folded in ----------------
__global__ __launch_bounds__(256) void k_maskadd(const int* __restrict__ mask,
                                                float* __restrict__ madd, int n) {
  const int i = blockIdx.x * 256 + threadIdx.x;
  if (i < n) madd[i] = mask[i] ? -8.0f : -1.442695041e9f;
}

// ---- flash attention v10: 8-wave blocks (256 q-rows), K/V staging split by wave ----
// Occupancy experiment: 512 blocks x 8 waves (vs 1024 x 4). Waves 0-3 stage K,
// waves 4-7 stage V -> exactly 1 gload/wave/tile, counted wait = vmcnt(1).
// Cross-wave visibility: each wave drains its OWN oldest load pre-barrier; after
// the barrier all waves' tile-t pieces are in LDS. Math identical to v9.
#define KSCALE 0.1803368801e0f  /* 0.125 * log2(e) */
__global__ __launch_bounds__(512) void k_attn10(
    const ushort_t* __restrict__ Qb, const ushort_t* __restrict__ Kb,
    const ushort_t* __restrict__ Vt, const float* __restrict__ madd,
    ushort_t* __restrict__ Ob) {
  __shared__ __align__(16) ushort_t Ks[3][32 * 64];  // 4KB x3
  __shared__ __align__(16) ushort_t Vs[3][64 * 32];  // 4KB x3
  __shared__ __align__(16) float Ms[Sc];             // 8KB (32KB total)

  const int bid = blockIdx.x;                // 512 blocks
  const int xcd = bid & 7, idx = bid >> 3;   // 64 per XCD
  const int bh = xcd * 8 + (idx >> 3);       // 8 heads per XCD band
  const int qb = idx & 7;                    // 8 q-blocks of 256 rows
  const int b = bh >> 4, h = bh & 15;
  const int tid = threadIdx.x;
  const int lane = tid & 63, w = tid >> 6;   // 8 waves
  const int l31 = lane & 31, hi = lane >> 5;
  const size_t bS = (size_t)b * Sc;
  const int qrow0 = qb * 256 + w * 32;

  bf16x8 qf[4];
  const ushort_t* qp = Qb + (bS + qrow0 + l31) * Dc + h * DKc + hi * 8;
#pragma unroll
  for (int c = 0; c < 4; ++c) qf[c] = *(const bf16x8*)(qp + c * 16);

  bf16x8 ones;
#pragma unroll
  for (int i = 0; i < 8; ++i) ones[i] = (short)0x3F80;

  f32x16 accA, accB, accS;
#pragma unroll
  for (int i = 0; i < 16; ++i) { accA[i] = 0.f; accB[i] = 0.f; accS[i] = 0.f; }

  const ushort_t* Vth = Vt + (size_t)bh * (DKc * Sc);
  const float* mp = madd + b * Sc;

  // staging geometry: chunk c = tid&255; K by waves 0-3, V by waves 4-7.
  const int c0 = tid & 255;
  const int kr = c0 >> 3, ksl = (c0 & 7) ^ (kr & 7);
  const int vr = c0 >> 2, vsl = (c0 & 3) ^ ((vr >> 1) & 3);
  const ushort_t* Kg = Kb + (bS + kr) * Dc + h * DKc + ksl * 8;   // + kv2*Dc
  const ushort_t* Vg = Vth + (size_t)vr * Sc + vsl * 8;           // + kv2
  char* const k_w = (char*)(&Ks[0][0]) + (w & 3) * 1024;          // + bi*4096
  char* const v_w = (char*)(&Vs[0][0]) + (w & 3) * 1024;

  // mask row -> LDS (512 chunks of 16B, 1 per thread), then stage tiles 0,1
  gload_lds16(mp + tid * 4, (char*)Ms + w * 1024);
  if (w < 4) {
    gload_lds16(Kg, k_w);
    gload_lds16(Kg + (size_t)32 * Dc, k_w + 4096);
  } else {
    gload_lds16(Vg, v_w);
    gload_lds16(Vg + 32, v_w + 4096);
  }

  const int vsw = (l31 >> 1) & 3;
  int cur = 0;
  for (int t = 0; t < 64; ++t) {
    if (t < 63) { asm volatile("s_waitcnt vmcnt(1)" ::: "memory"); }
    else        { asm volatile("s_waitcnt vmcnt(0)" ::: "memory"); }
    asm volatile("s_barrier" ::: "memory");   // tile t (K+V+mask) resident
    const char* Kbuf = (const char*)(&Ks[cur][0]);
    const char* Vbuf = (const char*)(&Vs[cur][0]);
    bf16x8 kf[4];
#pragma unroll
    for (int c = 0; c < 4; ++c) {
      const int slr = (c * 2 + hi) ^ (l31 & 7);
      kf[c] = *(const bf16x8*)(Kbuf + l31 * 128 + slr * 16);
    }
    const bf16x8 v00 = *(const bf16x8*)(Vbuf + l31 * 64 + ((hi ^ vsw) * 16));
    const bf16x8 v01 = *(const bf16x8*)(Vbuf + l31 * 64 + (((2 + hi) ^ vsw) * 16));
    const bf16x8 v10 = *(const bf16x8*)(Vbuf + (32 + l31) * 64 + ((hi ^ vsw) * 16));
    const bf16x8 v11 = *(const bf16x8*)(Vbuf + (32 + l31) * 64 + (((2 + hi) ^ vsw) * 16));
    float4 mv[4];
#pragma unroll
    for (int c = 0; c < 4; ++c)
      mv[c] = *(const float4*)(&Ms[t * 32 + c * 8 + 4 * hi]);
    if (t + 2 < 64) {                 // stage tile t+2 (buffer read finished at t-1)
      const int bi = (cur + 2 >= 3) ? cur - 1 : cur + 2;
      const size_t kv2 = (size_t)(t + 2) * 32;
      if (w < 4) gload_lds16(Kg + kv2 * Dc, k_w + bi * 4096);
      else       gload_lds16(Vg + kv2, v_w + bi * 4096);
    }
    // QK^T (swapped): C[kv][q]
    f32x16 sc;
#pragma unroll
    for (int i = 0; i < 16; ++i) sc[i] = 0.f;
    __builtin_amdgcn_s_setprio(1);
    sc = __builtin_amdgcn_mfma_f32_32x32x16_bf16(kf[0], qf[0], sc, 0, 0, 0);
    sc = __builtin_amdgcn_mfma_f32_32x32x16_bf16(kf[1], qf[1], sc, 0, 0, 0);
    sc = __builtin_amdgcn_mfma_f32_32x32x16_bf16(kf[2], qf[2], sc, 0, 0, 0);
    sc = __builtin_amdgcn_mfma_f32_32x32x16_bf16(kf[3], qf[3], sc, 0, 0, 0);
    __builtin_amdgcn_s_setprio(0);
    // fixed-max softmax: p = exp2(sc*KSCALE + madd)
    float p[16];
    p[0] = exp2f(sc[0] * KSCALE + mv[0].x);  p[1] = exp2f(sc[1] * KSCALE + mv[0].y);
    p[2] = exp2f(sc[2] * KSCALE + mv[0].z);  p[3] = exp2f(sc[3] * KSCALE + mv[0].w);
    p[4] = exp2f(sc[4] * KSCALE + mv[1].x);  p[5] = exp2f(sc[5] * KSCALE + mv[1].y);
    p[6] = exp2f(sc[6] * KSCALE + mv[1].z);  p[7] = exp2f(sc[7] * KSCALE + mv[1].w);
    p[8] = exp2f(sc[8] * KSCALE + mv[2].x);  p[9] = exp2f(sc[9] * KSCALE + mv[2].y);
    p[10] = exp2f(sc[10] * KSCALE + mv[2].z); p[11] = exp2f(sc[11] * KSCALE + mv[2].w);
    p[12] = exp2f(sc[12] * KSCALE + mv[3].x); p[13] = exp2f(sc[13] * KSCALE + mv[3].y);
    p[14] = exp2f(sc[14] * KSCALE + mv[3].z); p[15] = exp2f(sc[15] * KSCALE + mv[3].w);
    // P -> bf16 A-frags
    unsigned cw[4][2];
#pragma unroll
    for (int a = 0; a < 4; ++a) {
      cw[a][0] = cvtpk_bf16(p[4 * a + 0], p[4 * a + 1]);
      cw[a][1] = cvtpk_bf16(p[4 * a + 2], p[4 * a + 3]);
    }
    unsigned a00 = cw[0][0], b00 = cw[1][0]; swapl(a00, b00);
    unsigned a01 = cw[0][1], b01 = cw[1][1]; swapl(a01, b01);
    unsigned a10 = cw[2][0], b10 = cw[3][0]; swapl(a10, b10);
    unsigned a11 = cw[2][1], b11 = cw[3][1]; swapl(a11, b11);
    union { unsigned u[4]; bf16x8 v; } pa0, pa1;
    pa0.u[0] = a00; pa0.u[1] = a01; pa0.u[2] = b00; pa0.u[3] = b01;
    pa1.u[0] = a10; pa1.u[1] = a11; pa1.u[2] = b10; pa1.u[3] = b11;
    // PV + rowsum
    __builtin_amdgcn_s_setprio(1);
    accA = __builtin_amdgcn_mfma_f32_32x32x16_bf16(pa0.v, v00, accA, 0, 0, 0);
    accA = __builtin_amdgcn_mfma_f32_32x32x16_bf16(pa1.v, v01, accA, 0, 0, 0);
    accB = __builtin_amdgcn_mfma_f32_32x32x16_bf16(pa0.v, v10, accB, 0, 0, 0);
    accB = __builtin_amdgcn_mfma_f32_32x32x16_bf16(pa1.v, v11, accB, 0, 0, 0);
    accS = __builtin_amdgcn_mfma_f32_32x32x16_bf16(pa0.v, ones, accS, 0, 0, 0);
    accS = __builtin_amdgcn_mfma_f32_32x32x16_bf16(pa1.v, ones, accS, 0, 0, 0);
    __builtin_amdgcn_s_setprio(0);
    cur = (cur + 1 == 3) ? 0 : cur + 1;
  }

  // epilogue: accS[r] lane-uniform rowsum
#pragma unroll
  for (int r = 0; r < 16; ++r) {
    const int q = (r & 3) + 8 * (r >> 2) + 4 * hi;
    const float inv = 1.0f / accS[r];
    ushort_t* op = Ob + (bS + qrow0 + q) * Dc + h * DKc + l31;
    op[0] = f2bf(accA[r] * inv);
    op[32] = f2bf(accB[r] * inv);
  }
}

// ---------------- launcher ----------------
extern "C" void kernel_launch(void* const* d_in, const int* in_sizes, int n_in,
                              void* d_out, int out_size, void* d_ws, size_t ws_size,
                              hipStream_t stream) {
  const float* x     = (const float*)d_in[0];
  const int* mask    = (const int*)d_in[1];
  const float* wq_w  = (const float*)d_in[2];
  const float* wq_b  = (const float*)d_in[3];
  const float* wk_w  = (const float*)d_in[4];
  const float* wk_b  = (const float*)d_in[5];
  const float* wv_w  = (const float*)d_in[6];
  const float* wv_b  = (const float*)d_in[7];
  const float* wo_w  = (const float*)d_in[8];
  const float* wo_b  = (const float*)d_in[9];
  const float* ff_w0 = (const float*)d_in[10];
  const float* ff_b0 = (const float*)d_in[11];
  const float* ff_w1 = (const float*)d_in[12];
  const float* ff_b1 = (const float*)d_in[13];
  const float* ln0_a = (const float*)d_in[14];
  const float* ln0_b = (const float*)d_in[15];
  const float* ln1_a = (const float*)d_in[16];
  const float* ln1_b = (const float*)d_in[17];
  float* out = (float*)d_out;

  char* ws = (char*)d_ws;
  size_t off = 0;
  ushort_t* WTq = (ushort_t*)(ws + off); off += (size_t)Dc * Dc * 2;   // [3072,1024] packed
  ushort_t* WTk = (ushort_t*)(ws + off); off += (size_t)Dc * Dc * 2;
  ushort_t* WTv = (ushort_t*)(ws + off); off += (size_t)Dc * Dc * 2;
  ushort_t* WTo = (ushort_t*)(ws + off); off += (size_t)Dc * Dc * 2;
  ushort_t* WT0 = (ushort_t*)(ws + off); off += (size_t)DFFc * Dc * 2;
  ushort_t* WT1 = (ushort_t*)(ws + off); off += (size_t)Dc * DFFc * 2;
  ushort_t* hbuf = (ushort_t*)(ws + off); off += (size_t)Mc * Dc * 2;
  ushort_t* qbuf = (ushort_t*)(ws + off); off += (size_t)Mc * Dc * 2;
  ushort_t* kbuf = (ushort_t*)(ws + off); off += (size_t)Mc * Dc * 2;
  ushort_t* vtb  = (ushort_t*)(ws + off); off += (size_t)Mc * Dc * 2;  // Vt [B,H,DK,S]
  ushort_t* abuf = (ushort_t*)(ws + off); off += (size_t)Mc * Dc * 2;
  float* maddb   = (float*)(ws + off);   off += (size_t)Bc * Sc * 4;
  ushort_t* gbuf = qbuf;  // overlays dead q/k/vt buffers

  const dim3 blk(256);
  const dim3 blk512(512);
  k_transpose_cvt<<<dim3(Dc / 32, Dc / 32), blk, 0, stream>>>(wq_w, WTq, Dc, Dc);
  k_transpose_cvt<<<dim3(Dc / 32, Dc / 32), blk, 0, stream>>>(wk_w, WTk, Dc, Dc);
  k_transpose_cvt<<<dim3(Dc / 32, Dc / 32), blk, 0, stream>>>(wv_w, WTv, Dc, Dc);
  k_transpose_cvt<<<dim3(Dc / 32, Dc / 32), blk, 0, stream>>>(wo_w, WTo, Dc, Dc);
  k_transpose_cvt<<<dim3(DFFc / 32, Dc / 32), blk, 0, stream>>>(ff_w0, WT0, Dc, DFFc);
  k_transpose_cvt<<<dim3(Dc / 32, DFFc / 32), blk, 0, stream>>>(ff_w1, WT1, DFFc, Dc);
  k_maskadd<<<dim3((Bc * Sc + 255) / 256), blk, 0, stream>>>(mask, maddb, Bc * Sc);
  // LN0
  k_layernorm<<<Mc, blk, 0, stream>>>(x, ln0_a, ln0_b, hbuf);
  // fused QKV projection
  k_gemm8<4><<<dim3(768), blk512, 0, stream>>>(hbuf, WTq, wq_b, wk_b, wv_b, nullptr,
                                               qbuf, kbuf, vtb, 3072, Dc, 3);
  // attention (8-wave blocks, K/V staging split by wave, vmcnt(1))
  k_attn10<<<dim3(512), blk512, 0, stream>>>(qbuf, kbuf, vtb, maddb, abuf);
  // O projection + residual(x) -> d_out (f32)
  k_gemm8<1><<<dim3(256), blk512, 0, stream>>>(abuf, WTo, wo_b, nullptr, nullptr, x,
                                               out, nullptr, nullptr, Dc, Dc, 1);
  // LN1
  k_layernorm<<<Mc, blk, 0, stream>>>(out, ln1_a, ln1_b, hbuf);
  // FFN0 + tanh-GELU -> gbuf (bf16)
  k_gemm8<2><<<dim3(1024), blk512, 0, stream>>>(hbuf, WT0, ff_b0, nullptr, nullptr, nullptr,
                                                gbuf, nullptr, nullptr, DFFc, Dc, 4);
  // FFN1 + residual(d_out) -> d_out (f32)
  k_gemm8<1><<<dim3(256), blk512, 0, stream>>>(gbuf, WT1, ff_b1, nullptr, nullptr, out,
                                               out, nullptr, nullptr, Dc, DFFc, 1);
}